// Round 11
// baseline (52.462 us; speedup 1.0000x reference)
//
#include <hip/hip_runtime.h>

typedef _Float16 h8     __attribute__((ext_vector_type(8)));
typedef float    f32x16 __attribute__((ext_vector_type(16)));

#define BB      16
#define NPTS    4096
#define WAVES   4                       // waves per block
#define RPW     64                      // rows per wave = 2 row-blocks of 32
#define RPB     (WAVES * RPW)           // 256 rows per block
#define CSPLIT  4                       // column split across blocks
#define COLS    (NPTS / CSPLIT)         // 1024 cols per block
#define CHUNK   256                     // cols staged per LDS chunk
#define NCHUNK  (COLS / CHUNK)          // 4
#define TPB     (WAVES * 64)            // 256

__global__ __launch_bounds__(256) void chamfer_init_out(float* __restrict__ out) {
    int i = blockIdx.x * 256 + threadIdx.x;
    out[i] = 3.0e38f;
}

// Fold one f32x16 to a scalar min (tree; clang fuses to v_min3 where legal).
__device__ __forceinline__ float vmin16(const f32x16& v) {
    float a = fminf(fminf(v[0], v[1]), fminf(v[2], v[3]));
    float b = fminf(fminf(v[4], v[5]), fminf(v[6], v[7]));
    float c = fminf(fminf(v[8], v[9]), fminf(v[10], v[11]));
    float d = fminf(fminf(v[12], v[13]), fminf(v[14], v[15]));
    return fminf(fminf(a, b), fminf(c, d));
}

// FUSED chamfer: each 32x32 d2 tile is computed ONCE; row-min -> dist1,
// col-min -> dist2 (C/D map col=lane&31, row=(r&3)+8*(r>>2)+4*(lane>>5),
// proven R6-R9). K=13 fp16-split dot as R6-R9 (absmax ~1e-3):
//  A half0 = [xh,yh,zh, xh,yh,zh, xl,yl]   A half1 = [zl, s1h,s1l, 1,1, 0,0,0]
//  B half0 = [-2xh,-2yh,-2zh, -2xl,-2yl,-2zl, -2xh,-2yh]
//  B half1 = [-2zh, 1,1, s2h,s2l, 0,0,0]
// LDS sb: tile t, k-half hf, col c: half-off = t*512 + hf*256 + (c&31)*8
//  -> wave ds_read_b128 linear 1024B, conflict-free (verified R7/R8).
// R10 lesson: NO inline asm on MFMA results, NO manual pipelining.
// R8 lesson: transients capped (2 f32x16 live) + unroll 1 -> no spill.
__global__ __launch_bounds__(TPB, 4) void chamfer_mfma(
    const float* __restrict__ xyz1,
    const float* __restrict__ xyz2,
    float* __restrict__ out)
{
    __shared__ __align__(16) _Float16 sb[2][CHUNK * 16];   // 16 KB
    __shared__ float colw[WAVES][COLS];                    // 16 KB, per-wave col partials

    const int tid  = threadIdx.x;
    const int lane = tid & 63;
    const int wv   = tid >> 6;
    const int rb   = blockIdx.x;       // row-block 0..15 (rows from set1)
    const int b    = blockIdx.y;       // batch
    const int csp  = blockIdx.z;       // col split 0..CSPLIT-1 (cols from set2)

    const float* qbase = xyz1 + b * NPTS * 3;
    const float* dbase = xyz2 + b * NPTS * 3 + csp * COLS * 3;

    // ---- two A fragments per wave (row-blocks of 32, rows from set1) ----
    h8 af0, af1;
#pragma unroll
    for (int rbi = 0; rbi < 2; ++rbi) {
        const int row = rb * RPB + wv * RPW + rbi * 32 + (lane & 31);
        float x = qbase[row * 3 + 0], y = qbase[row * 3 + 1], z2 = qbase[row * 3 + 2];
        float s = fmaf(x, x, fmaf(y, y, z2 * z2));
        _Float16 xh = (_Float16)x, yh = (_Float16)y, zh = (_Float16)z2;
        _Float16 xl = (_Float16)(x - (float)xh);
        _Float16 yl = (_Float16)(y - (float)yh);
        _Float16 zl = (_Float16)(z2 - (float)zh);
        _Float16 sh = (_Float16)s;
        _Float16 sl = (_Float16)(s - (float)sh);
        _Float16 one = (_Float16)1.0f, zero = (_Float16)0.0f;
        h8 a = (lane < 32) ? h8{xh, yh, zh, xh, yh, zh, xl, yl}
                           : h8{zl, sh, sl, one, one, zero, zero, zero};
        if (rbi == 0) af0 = a; else af1 = a;
    }

    // ---- init per-wave col partial array ----
    for (int i = tid; i < WAVES * COLS; i += TPB) ((float*)colw)[i] = 3.0e38f;

    const f32x16 Z = {};
    float rm0[16], rm1[16];
#pragma unroll
    for (int r = 0; r < 16; ++r) { rm0[r] = 3.0e38f; rm1[r] = 3.0e38f; }

    const int loff = ((lane >> 5) << 8) + (lane & 31) * 8;   // halfs

    // ---- staging: one col per thread per chunk (CHUNK == TPB) ----
    float vx, vy, vz;
    auto stage_load = [&](int ch) {
        const float* p = dbase + (ch * CHUNK + tid) * 3;
        vx = p[0]; vy = p[1]; vz = p[2];
    };
    auto stage_write = [&](int buf) {
        float s = fmaf(vx, vx, fmaf(vy, vy, vz * vz));
        _Float16 xh = (_Float16)vx, yh = (_Float16)vy, zh = (_Float16)vz;
        _Float16 m2xh = (_Float16)(-2.0f) * xh;
        _Float16 m2yh = (_Float16)(-2.0f) * yh;
        _Float16 m2zh = (_Float16)(-2.0f) * zh;
        _Float16 m2xl = (_Float16)(-2.0f * (vx - (float)xh));
        _Float16 m2yl = (_Float16)(-2.0f * (vy - (float)yh));
        _Float16 m2zl = (_Float16)(-2.0f * (vz - (float)zh));
        _Float16 sh = (_Float16)s;
        _Float16 sl = (_Float16)(s - (float)sh);
        _Float16 one = (_Float16)1.0f, zero = (_Float16)0.0f;
        int off = (tid >> 5) * 512 + (tid & 31) * 8;
        *(h8*)&sb[buf][off]       = h8{m2xh, m2yh, m2zh, m2xl, m2yl, m2zl, m2xh, m2yh};
        *(h8*)&sb[buf][off + 256] = h8{m2zh, one, one, sh, sl, zero, zero, zero};
    };

    // ---- sweep: one 32-col tile per iteration; both row- and col-mins ----
    auto sweep = [&](int buf, int ch) {
        const _Float16* base = &sb[buf][0];
#pragma unroll 1
        for (int t = 0; t < CHUNK / 32; ++t) {
            h8 bt = *(const h8*)(base + t * 512 + loff);
            f32x16 c0 = __builtin_amdgcn_mfma_f32_32x32x16_f16(af0, bt, Z, 0, 0, 0);
            f32x16 c1 = __builtin_amdgcn_mfma_f32_32x32x16_f16(af1, bt, Z, 0, 0, 0);
            // row accumulate
#pragma unroll
            for (int r = 0; r < 16; ++r) rm0[r] = fminf(c0[r], rm0[r]);
#pragma unroll
            for (int r = 0; r < 16; ++r) rm1[r] = fminf(c1[r], rm1[r]);
            // col partial: min over 32 regs (rows of both row-blocks, this half)
            float p = fminf(vmin16(c0), vmin16(c1));
            // combine lane-halves (same col, other 32 rows... i.e. other reg-rows)
            p = fminf(p, __shfl_xor(p, 32));
            if (lane < 32)
                colw[wv][ch * CHUNK + t * 32 + lane] = fmaxf(p, 0.0f);
        }
    };

    stage_load(0);
    stage_write(0);
    __syncthreads();
#pragma unroll 1
    for (int ch = 0; ch < NCHUNK; ++ch) {
        int buf = ch & 1;
        if (ch + 1 < NCHUNK) stage_load(ch + 1);
        sweep(buf, ch);
        if (ch + 1 < NCHUNK) stage_write(buf ^ 1);
        __syncthreads();
    }

    // ---- dist1: butterfly over 32 col-lanes, atomic per row ----
#pragma unroll
    for (int r = 0; r < 16; ++r) {
        float m = rm0[r];
        m = fminf(m, __shfl_xor(m, 1));
        m = fminf(m, __shfl_xor(m, 2));
        m = fminf(m, __shfl_xor(m, 4));
        m = fminf(m, __shfl_xor(m, 8));
        m = fminf(m, __shfl_xor(m, 16));
        rm0[r] = m;
        float n = rm1[r];
        n = fminf(n, __shfl_xor(n, 1));
        n = fminf(n, __shfl_xor(n, 2));
        n = fminf(n, __shfl_xor(n, 4));
        n = fminf(n, __shfl_xor(n, 8));
        n = fminf(n, __shfl_xor(n, 16));
        rm1[r] = n;
    }
    if ((lane & 31) == 0) {
        const int half = lane >> 5;
        int* o = (int*)out + b * NPTS + rb * RPB + wv * RPW;
#pragma unroll
        for (int r = 0; r < 16; ++r) {
            int rr = (r & 3) + 8 * (r >> 2) + 4 * half;   // C/D row map (m74/m101)
            atomicMin(o + rr,      __float_as_int(fmaxf(rm0[r], 0.0f)));
            atomicMin(o + 32 + rr, __float_as_int(fmaxf(rm1[r], 0.0f)));
        }
    }

    // ---- dist2: reduce per-wave col partials, atomic per col ----
    // (last loop iteration ended with __syncthreads -> colw complete)
    int* o2 = (int*)out + BB * NPTS + b * NPTS + csp * COLS;
#pragma unroll
    for (int k = 0; k < COLS / TPB; ++k) {
        int i = tid + k * TPB;
        float m = fminf(fminf(colw[0][i], colw[1][i]),
                        fminf(colw[2][i], colw[3][i]));
        atomicMin(o2 + i, __float_as_int(m));
    }
}

extern "C" void kernel_launch(void* const* d_in, const int* in_sizes, int n_in,
                              void* d_out, int out_size, void* d_ws, size_t ws_size,
                              hipStream_t stream) {
    const float* xyz1 = (const float*)d_in[0];
    const float* xyz2 = (const float*)d_in[1];
    float* out = (float*)d_out;

    // init output to +big (harness poisons d_out; must rewrite every call)
    hipLaunchKernelGGL(chamfer_init_out, dim3(2 * BB * NPTS / 256), dim3(256), 0, stream, out);

    dim3 grid(NPTS / RPB, BB, CSPLIT);   // 16 x 16 x 4 = 1024 blocks
    hipLaunchKernelGGL(chamfer_mfma, grid, dim3(TPB), 0, stream, xyz1, xyz2, out);
}

// Round 12
// 34.177 us; speedup vs baseline: 1.5350x; 1.5350x over previous
//
#include <hip/hip_runtime.h>

typedef _Float16 h8     __attribute__((ext_vector_type(8)));
typedef float    f32x16 __attribute__((ext_vector_type(16)));

#define BB      16
#define NPTS    4096
#define WAVES   4                       // waves per block
#define RPW     64                      // rows per wave = 2 row-blocks of 32
#define RPB     (WAVES * RPW)           // 256 rows per block
#define CSPLIT  2                       // column split across blocks
#define COLS    (NPTS / CSPLIT)         // 2048 cols per block
#define CHUNK   256                     // cols staged per LDS chunk
#define NCHUNK  (COLS / CHUNK)          // 8
#define NT      (CHUNK / 32)            // 8 b-tiles per chunk
#define TPB     (WAVES * 64)            // 256

__global__ __launch_bounds__(256) void chamfer_init_out(float* __restrict__ out) {
    int i = blockIdx.x * 256 + threadIdx.x;
    out[i] = 3.0e38f;
}

// d2(a,b) = s1 + s2 - 2 a.b via K=13 fp16-split dot (proven R6-R9, absmax ~1e-3):
//  A half0 = [xh,yh,zh, xh,yh,zh, xl,yl]   A half1 = [zl, s1h,s1l, 1,1, 0,0,0]
//  B half0 = [-2xh,-2yh,-2zh, -2xl,-2yl,-2zl, -2xh,-2yh]
//  B half1 = [-2zh, 1,1, s2h,s2l, 0,0,0]
// LDS sb: tile t, k-half hf, col c: half-off = t*512 + hf*256 + (c&31)*8
//  -> wave ds_read_b128 linear 1024B, conflict-free (verified R7/R8).
// R10 lesson: no inline asm touching MFMA results. R11 lesson: no col-fusion
// (serial fold + shfl in inner loop). R12: pure-C 2-stage pipeline -- fold
// PREVIOUS tile's pair while current tile's MFMAs are in flight; issue/fold
// interleaved (pB0 -> fold pA0 -> pB1 -> fold pA1) caps live f32x16 at 3.
__global__ __launch_bounds__(TPB, 4) void chamfer_mfma(
    const float* __restrict__ xyz1,
    const float* __restrict__ xyz2,
    float* __restrict__ out)
{
    __shared__ __align__(16) _Float16 sb[2][CHUNK * 16];   // 2 x 8 KB

    const int tid  = threadIdx.x;
    const int lane = tid & 63;
    const int wv   = tid >> 6;
    const int rb   = blockIdx.x;       // row-block 0..15
    const int b    = blockIdx.y;       // batch
    const int z    = blockIdx.z;       // dir + col-split
    const int dir  = z & 1;
    const int csp  = z >> 1;           // 0..CSPLIT-1

    const float* qbase = (dir == 0 ? xyz1 : xyz2) + b * NPTS * 3;
    const float* dbase = (dir == 0 ? xyz2 : xyz1) + b * NPTS * 3 + csp * COLS * 3;

    // ---- two A fragments per wave (row-blocks of 32) ----
    h8 af0, af1;
#pragma unroll
    for (int rbi = 0; rbi < 2; ++rbi) {
        const int row = rb * RPB + wv * RPW + rbi * 32 + (lane & 31);
        float x = qbase[row * 3 + 0], y = qbase[row * 3 + 1], z2 = qbase[row * 3 + 2];
        float s = fmaf(x, x, fmaf(y, y, z2 * z2));
        _Float16 xh = (_Float16)x, yh = (_Float16)y, zh = (_Float16)z2;
        _Float16 xl = (_Float16)(x - (float)xh);
        _Float16 yl = (_Float16)(y - (float)yh);
        _Float16 zl = (_Float16)(z2 - (float)zh);
        _Float16 sh = (_Float16)s;
        _Float16 sl = (_Float16)(s - (float)sh);
        _Float16 one = (_Float16)1.0f, zero = (_Float16)0.0f;
        h8 a = (lane < 32) ? h8{xh, yh, zh, xh, yh, zh, xl, yl}
                           : h8{zl, sh, sl, one, one, zero, zero, zero};
        if (rbi == 0) af0 = a; else af1 = a;
    }

    const f32x16 Z = {};
    float rm0[16], rm1[16];
#pragma unroll
    for (int r = 0; r < 16; ++r) { rm0[r] = 3.0e38f; rm1[r] = 3.0e38f; }

    const int loff = ((lane >> 5) << 8) + (lane & 31) * 8;   // halfs

    // ---- staging: one col per thread per chunk (CHUNK == TPB) ----
    float vx, vy, vz;
    auto stage_load = [&](int ch) {
        const float* p = dbase + (ch * CHUNK + tid) * 3;
        vx = p[0]; vy = p[1]; vz = p[2];
    };
    auto stage_write = [&](int buf) {
        float s = fmaf(vx, vx, fmaf(vy, vy, vz * vz));
        _Float16 xh = (_Float16)vx, yh = (_Float16)vy, zh = (_Float16)vz;
        _Float16 m2xh = (_Float16)(-2.0f) * xh;
        _Float16 m2yh = (_Float16)(-2.0f) * yh;
        _Float16 m2zh = (_Float16)(-2.0f) * zh;
        _Float16 m2xl = (_Float16)(-2.0f * (vx - (float)xh));
        _Float16 m2yl = (_Float16)(-2.0f * (vy - (float)yh));
        _Float16 m2zl = (_Float16)(-2.0f * (vz - (float)zh));
        _Float16 sh = (_Float16)s;
        _Float16 sl = (_Float16)(s - (float)sh);
        _Float16 one = (_Float16)1.0f, zero = (_Float16)0.0f;
        int off = (tid >> 5) * 512 + (tid & 31) * 8;
        *(h8*)&sb[buf][off]       = h8{m2xh, m2yh, m2zh, m2xl, m2yl, m2zl, m2xh, m2yh};
        *(h8*)&sb[buf][off + 256] = h8{m2zh, one, one, sh, sl, zero, zero, zero};
    };

#define FOLD0(p) _Pragma("unroll") for (int r = 0; r < 16; ++r) rm0[r] = fminf((p)[r], rm0[r]);
#define FOLD1(p) _Pragma("unroll") for (int r = 0; r < 16; ++r) rm1[r] = fminf((p)[r], rm1[r]);

    // ---- sweep with 2-stage software pipeline (pure C) ----
    auto sweep = [&](int buf) {
        const _Float16* base = &sb[buf][0];
        // prologue: tile 0
        h8 b0 = *(const h8*)(base + loff);
        f32x16 pA0 = __builtin_amdgcn_mfma_f32_32x32x16_f16(af0, b0, Z, 0, 0, 0);
        f32x16 pA1 = __builtin_amdgcn_mfma_f32_32x32x16_f16(af1, b0, Z, 0, 0, 0);
#pragma unroll 1
        for (int t = 1; t + 1 < NT; t += 2) {
            h8 bx = *(const h8*)(base + t * 512 + loff);
            f32x16 pB0 = __builtin_amdgcn_mfma_f32_32x32x16_f16(af0, bx, Z, 0, 0, 0);
            FOLD0(pA0)
            f32x16 pB1 = __builtin_amdgcn_mfma_f32_32x32x16_f16(af1, bx, Z, 0, 0, 0);
            FOLD1(pA1)
            h8 by = *(const h8*)(base + (t + 1) * 512 + loff);
            pA0 = __builtin_amdgcn_mfma_f32_32x32x16_f16(af0, by, Z, 0, 0, 0);
            FOLD0(pB0)
            pA1 = __builtin_amdgcn_mfma_f32_32x32x16_f16(af1, by, Z, 0, 0, 0);
            FOLD1(pB1)
        }
        // tail: tile NT-1 (NT even -> one tile left), then drain
        {
            h8 bx = *(const h8*)(base + (NT - 1) * 512 + loff);
            f32x16 pB0 = __builtin_amdgcn_mfma_f32_32x32x16_f16(af0, bx, Z, 0, 0, 0);
            FOLD0(pA0)
            f32x16 pB1 = __builtin_amdgcn_mfma_f32_32x32x16_f16(af1, bx, Z, 0, 0, 0);
            FOLD1(pA1)
            FOLD0(pB0)
            FOLD1(pB1)
        }
    };

    stage_load(0);
    stage_write(0);
    __syncthreads();
#pragma unroll 1
    for (int ch = 0; ch < NCHUNK; ++ch) {
        int buf = ch & 1;
        if (ch + 1 < NCHUNK) stage_load(ch + 1);
        sweep(buf);
        if (ch + 1 < NCHUNK) stage_write(buf ^ 1);
        __syncthreads();
    }

    // ---- reduce over 32 col-lanes (butterfly within each half) ----
#pragma unroll
    for (int r = 0; r < 16; ++r) {
        float m = rm0[r];
        m = fminf(m, __shfl_xor(m, 1));
        m = fminf(m, __shfl_xor(m, 2));
        m = fminf(m, __shfl_xor(m, 4));
        m = fminf(m, __shfl_xor(m, 8));
        m = fminf(m, __shfl_xor(m, 16));
        rm0[r] = m;
        float n = rm1[r];
        n = fminf(n, __shfl_xor(n, 1));
        n = fminf(n, __shfl_xor(n, 2));
        n = fminf(n, __shfl_xor(n, 4));
        n = fminf(n, __shfl_xor(n, 8));
        n = fminf(n, __shfl_xor(n, 16));
        rm1[r] = n;
    }
    // ---- combine across col-splits via int atomicMin (values >= 0) ----
    if ((lane & 31) == 0) {
        const int half = lane >> 5;
        int* o = (int*)out + dir * (BB * NPTS) + b * NPTS + rb * RPB + wv * RPW;
#pragma unroll
        for (int r = 0; r < 16; ++r) {
            int rr = (r & 3) + 8 * (r >> 2) + 4 * half;   // C/D row map (m74/m101)
            atomicMin(o + rr,      __float_as_int(fmaxf(rm0[r], 0.0f)));
            atomicMin(o + 32 + rr, __float_as_int(fmaxf(rm1[r], 0.0f)));
        }
    }
}

extern "C" void kernel_launch(void* const* d_in, const int* in_sizes, int n_in,
                              void* d_out, int out_size, void* d_ws, size_t ws_size,
                              hipStream_t stream) {
    const float* xyz1 = (const float*)d_in[0];
    const float* xyz2 = (const float*)d_in[1];
    float* out = (float*)d_out;

    // init output to +big (harness poisons d_out; must rewrite every call)
    hipLaunchKernelGGL(chamfer_init_out, dim3(2 * BB * NPTS / 256), dim3(256), 0, stream, out);

    dim3 grid(NPTS / RPB, BB, 2 * CSPLIT);   // 16 x 16 x 4 = 1024 blocks
    hipLaunchKernelGGL(chamfer_mfma, grid, dim3(TPB), 0, stream, xyz1, xyz2, out);
}